// Round 9
// baseline (115.860 us; speedup 1.0000x reference)
//
#include <hip/hip_runtime.h>

#define D 64
#define K 512
#define NT (K / 16)          // 32 codeword tiles
#define HNT (NT / 2)         // 16 tiles per codebook half
#define TAU 0.01f            // proxy-margin threshold (dist-gap 0.02)

typedef float  f32x4  __attribute__((ext_vector_type(4)));
typedef short  bf16x8 __attribute__((ext_vector_type(8)));

__device__ inline unsigned short bf16_rne(float f) {
    union { float f; unsigned u; } v; v.f = f;
    unsigned r = v.u + 0x7FFFu + ((v.u >> 16) & 1u);
    return (unsigned short)(r >> 16);
}
__device__ inline float bf16_val(unsigned short b) {
    union { float f; unsigned u; } v; v.u = ((unsigned)b) << 16;
    return v.f;
}
__device__ inline void split8(const float* p, bf16x8& h, bf16x8& l) {
    float4 a = *(const float4*)p;
    float4 b = *(const float4*)(p + 4);
    float f[8] = {a.x, a.y, a.z, a.w, b.x, b.y, b.z, b.w};
#pragma unroll
    for (int j = 0; j < 8; ++j) {
        unsigned short hb = bf16_rne(f[j]);
        float lo = f[j] - bf16_val(hb);
        h[j] = (short)hb;
        l[j] = (short)bf16_rne(lo);
    }
}

// Prep (4096 threads): fragment-linear bf16 hi/lo B-operand from emb
// ((D,K) = B[k_gemm=d][n=codeword] directly), plus embT + ||e||^2.
__global__ void vq_prep(const float* __restrict__ emb,
                        float* __restrict__ embT,
                        float* __restrict__ enorm,
                        bf16x8* __restrict__ bhi,
                        bf16x8* __restrict__ blo) {
    int t = blockIdx.x * blockDim.x + threadIdx.x;   // 0..4095
    int nt = t >> 7, c = (t >> 6) & 1, lane = t & 63;
    int k  = nt * 16 + (lane & 15);
    int d0 = c * 32 + ((lane >> 4) << 3);
    bf16x8 h, l;
#pragma unroll
    for (int j = 0; j < 8; ++j) {
        float xv = emb[(d0 + j) * K + k];
        unsigned short hb = bf16_rne(xv);
        float lo = xv - bf16_val(hb);
        h[j] = (short)hb;
        l[j] = (short)bf16_rne(lo);
    }
    int off = (nt * 2 + c) * 64 + lane;
    bhi[off] = h; blo[off] = l;

    if (t < K) {    // job 2: transpose + norms
        float s = 0.f;
#pragma unroll
        for (int d = 0; d < D; ++d) {
            float v = emb[d * K + t];
            embT[t * D + d] = v;
            s += v * v;
        }
        enorm[t] = s;
    }
}

// Block = 64 rows, 4 waves. Wave pair p=(wave>>1) owns rows [p*32,p*32+32);
// half h=(wave&1) scans codebook tiles [h*16, h*16+16). 1024 blocks = 4
// blocks/CU. (Round-8 post-mortem: this exact kernel PASSED in round 7 at
// launch_bounds(256,4) but spilled to VGPR=64 / FETCH 3x; the ONLY change
// here is (256,2) so the allocator keeps fragments+accumulators resident.
// The round-7-submitted 4-way rewrite failed re-validation and is abandoned.)
// Proxy = -0.5*||e||^2 + x.e via 3-product bf16-split MFMA, 6 independent
// depth-2 MFMA chains (hh/hl/lh seeded from invariant zero). Top-2 tracked;
// halves merged in LDS; margin<TAU rows re-solved exactly in fp32 inline.
__global__ __launch_bounds__(256, 2) void vq_mfma(
    const float* __restrict__ x,
    const float* __restrict__ embT,
    const float* __restrict__ enorm,
    const bf16x8* __restrict__ bhi,
    const bf16x8* __restrict__ blo,
    float* __restrict__ outq,
    float* __restrict__ outidx) {
    const int tid  = threadIdx.x;
    const int wave = __builtin_amdgcn_readfirstlane(tid >> 6);
    const int lane = tid & 63;
    const int col  = lane & 15;
    const int grp  = lane >> 4;
    const int pair = wave >> 1;          // row-pair 0/1
    const int half = wave & 1;           // codebook half 0/1
    const int rowB = blockIdx.x * 64;    // block's first row
    const int rt0  = (rowB >> 4) + pair * 2;  // first row-tile of this wave

    __shared__ float l1[2][64], l2[2][64];
    __shared__ int   li[2][64];
    __shared__ int   sfin[64];

    // A fragments (16x16x32): row m = lane&15, k = (lane>>4)*8 + j (+32*c)
    bf16x8 ah[2][2], al[2][2];
#pragma unroll
    for (int t = 0; t < 2; ++t) {
        const float* xr = x + (size_t)((rt0 + t) * 16 + col) * D + grp * 8;
        split8(xr,      ah[t][0], al[t][0]);
        split8(xr + 32, ah[t][1], al[t][1]);
    }

    float b1[2][4], b2[2][4];
    int   bi[2][4];
#pragma unroll
    for (int t = 0; t < 2; ++t)
#pragma unroll
        for (int q = 0; q < 4; ++q) {
            b1[t][q] = -3.4e38f; b2[t][q] = -3.4e38f; bi[t][q] = 0;
        }

    const f32x4 zero4 = {0.f, 0.f, 0.f, 0.f};
#pragma unroll 2
    for (int it = 0; it < HNT; ++it) {
        const int nt = half * HNT + it;
        int fo = (nt * 2) * 64 + lane;
        bf16x8 bh0 = bhi[fo], bh1 = bhi[fo + 64];
        bf16x8 bl0 = blo[fo], bl1 = blo[fo + 64];
        float env2 = enorm[nt * 16 + col] * -0.5f;
        int kk = nt * 16 + col;
#pragma unroll
        for (int t = 0; t < 2; ++t) {
            f32x4 hh = __builtin_amdgcn_mfma_f32_16x16x32_bf16(ah[t][0], bh0, zero4, 0, 0, 0);
            f32x4 hl = __builtin_amdgcn_mfma_f32_16x16x32_bf16(ah[t][0], bl0, zero4, 0, 0, 0);
            f32x4 lh = __builtin_amdgcn_mfma_f32_16x16x32_bf16(al[t][0], bh0, zero4, 0, 0, 0);
            hh = __builtin_amdgcn_mfma_f32_16x16x32_bf16(ah[t][1], bh1, hh, 0, 0, 0);
            hl = __builtin_amdgcn_mfma_f32_16x16x32_bf16(ah[t][1], bl1, hl, 0, 0, 0);
            lh = __builtin_amdgcn_mfma_f32_16x16x32_bf16(al[t][1], bh1, lh, 0, 0, 0);
#pragma unroll
            for (int q = 0; q < 4; ++q) {
                float v = (hh[q] + hl[q]) + (lh[q] + env2);
                bool gt = v > b1[t][q];                       // strict: first k wins
                b2[t][q] = fmaxf(b2[t][q], fminf(b1[t][q], v)); // uses OLD b1
                b1[t][q] = gt ? v : b1[t][q];
                bi[t][q] = gt ? kk : bi[t][q];
            }
        }
    }

    // reduce across the 16 codeword-columns within each 16-lane group
#pragma unroll
    for (int t = 0; t < 2; ++t)
#pragma unroll
        for (int q = 0; q < 4; ++q) {
            float v1 = b1[t][q], v2 = b2[t][q];
            int   i1 = bi[t][q];
#pragma unroll
            for (int m = 1; m <= 8; m <<= 1) {
                float o1 = __shfl_xor(v1, m);
                float o2 = __shfl_xor(v2, m);
                int   oi = __shfl_xor(i1, m);
                float nb2 = fmaxf(fminf(v1, o1), fmaxf(v2, o2));
                if (o1 > v1 || (o1 == v1 && oi < i1)) { v1 = o1; i1 = oi; }
                v2 = nb2;
            }
            b1[t][q] = v1; b2[t][q] = v2; bi[t][q] = i1;
        }

    // per-wave consensus -> LDS (rows this wave covers, its half)
#pragma unroll
    for (int t = 0; t < 2; ++t)
#pragma unroll
        for (int q = 0; q < 4; ++q)
            if (col == q) {
                int rib = pair * 32 + t * 16 + grp * 4 + q;
                l1[half][rib] = b1[t][q];
                l2[half][rib] = b2[t][q];
                li[half][rib] = bi[t][q];
            }
    __syncthreads();

    // combine halves + flag + exact re-solve: waves 0 and 2 (one per pair)
    if (half == 0) {
        int rib  = pair * 32 + (lane & 31);
        float a1 = l1[0][rib], h1 = l1[1][rib];
        float a2 = l2[0][rib], h2 = l2[1][rib];
        int   ai = li[0][rib], hi = li[1][rib];
        bool hw  = h1 > a1;                 // strict: tie -> lower-k half
        float fb1 = hw ? h1 : a1;
        int   fbi = hw ? hi : ai;
        float fb2 = fmaxf(fmaxf(a2, h2), fminf(a1, h1));
        if (lane < 32) {
            sfin[rib] = fbi;
            outidx[rowB + rib] = (float)fbi;
        }
        unsigned long long mask =
            __ballot((lane < 32) && (fb1 - fb2 < TAU));
        while (mask) {
            int bit = __ffsll((long long)mask) - 1;
            mask &= mask - 1;
            int ribf = pair * 32 + bit;            // wave-uniform
            int row  = rowB + ribf;
            const float4* x4 = (const float4*)(x + (size_t)row * D);
            // exact fp32: lane owns codewords lane*8..lane*8+7, x in 4 chunks
            float xn = 0.f;
            float dd[8];
#pragma unroll
            for (int kk = 0; kk < 8; ++kk) dd[kk] = 0.f;
#pragma unroll
            for (int c = 0; c < 4; ++c) {
                float4 xc0 = x4[c*4+0], xc1 = x4[c*4+1];
                float4 xc2 = x4[c*4+2], xc3 = x4[c*4+3];
                xn += xc0.x*xc0.x + xc0.y*xc0.y + xc0.z*xc0.z + xc0.w*xc0.w
                    + xc1.x*xc1.x + xc1.y*xc1.y + xc1.z*xc1.z + xc1.w*xc1.w
                    + xc2.x*xc2.x + xc2.y*xc2.y + xc2.z*xc2.z + xc2.w*xc2.w
                    + xc3.x*xc3.x + xc3.y*xc3.y + xc3.z*xc3.z + xc3.w*xc3.w;
#pragma unroll
                for (int kk = 0; kk < 8; ++kk) {
                    const float4* e4 =
                        (const float4*)(embT + (size_t)(lane * 8 + kk) * D) + c * 4;
                    float4 e0 = e4[0], e1 = e4[1], e2 = e4[2], e3 = e4[3];
                    dd[kk] += xc0.x*e0.x + xc0.y*e0.y + xc0.z*e0.z + xc0.w*e0.w
                            + xc1.x*e1.x + xc1.y*e1.y + xc1.z*e1.z + xc1.w*e1.w
                            + xc2.x*e2.x + xc2.y*e2.y + xc2.z*e2.z + xc2.w*e2.w
                            + xc3.x*e3.x + xc3.y*e3.y + xc3.z*e3.z + xc3.w*e3.w;
                }
            }
            float best = 3.4e38f; int bb = 0;
#pragma unroll
            for (int kk = 0; kk < 8; ++kk) {         // ascending k within lane
                int k = lane * 8 + kk;
                float dist = (xn + enorm[k]) - 2.0f * dd[kk];
                if (dist < best) { best = dist; bb = k; }
            }
#pragma unroll
            for (int mm = 1; mm <= 32; mm <<= 1) {
                float od = __shfl_xor(best, mm);
                int   oi = __shfl_xor(bb, mm);
                if (od < best || (od == best && oi < bb)) { best = od; bb = oi; }
            }
            if (lane == 0) {
                sfin[ribf] = bb;
                outidx[row] = (float)bb;
            }
        }
    }
    __syncthreads();

    // cooperative coalesced gather+write: 64 rows x 16 float4 = 1024 float4
    const float4* ef4 = (const float4*)embT;
    float4* oq4 = (float4*)(outq + (size_t)rowB * D);
#pragma unroll
    for (int i = 0; i < 4; ++i) {
        int f  = tid + i * 256;       // 0..1023
        int rr = f >> 4;
        int j  = f & 15;
        oq4[f] = ef4[sfin[rr] * 16 + j];
    }
}

extern "C" void kernel_launch(void* const* d_in, const int* in_sizes, int n_in,
                              void* d_out, int out_size, void* d_ws, size_t ws_size,
                              hipStream_t stream) {
    const float* x   = (const float*)d_in[0];   // (64,32,32,64) f32
    const float* emb = (const float*)d_in[1];   // (64,512) f32
    int nrows = in_sizes[0] / D;                // 65536

    char* w = (char*)d_ws;
    float*  embT   = (float*)w;   w += (size_t)K * D * 4;        // 128 KiB
    float*  enorm  = (float*)w;   w += (size_t)K * 4;            // 2 KiB
    bf16x8* bhi    = (bf16x8*)w;  w += (size_t)NT * 2 * 64 * 16; // 64 KiB
    bf16x8* blo    = (bf16x8*)w;                                 // 64 KiB

    float* outq   = (float*)d_out;
    float* outidx = (float*)d_out + (size_t)nrows * D;

    vq_prep<<<16, 256, 0, stream>>>(emb, embT, enorm, bhi, blo);
    vq_mfma<<<nrows / 64, 256, 0, stream>>>(x, embT, enorm, bhi, blo,
                                            outq, outidx);
}

// Round 10
// 68.929 us; speedup vs baseline: 1.6809x; 1.6809x over previous
//
#include <hip/hip_runtime.h>

#define D 64
#define K 512
#define NT (K / 16)          // 32 codeword tiles
#define TAU 0.01f            // proxy-margin threshold (dist-gap 0.02)

typedef float  f32x4  __attribute__((ext_vector_type(4)));
typedef short  bf16x8 __attribute__((ext_vector_type(8)));

__device__ inline unsigned short bf16_rne(float f) {
    union { float f; unsigned u; } v; v.f = f;
    unsigned r = v.u + 0x7FFFu + ((v.u >> 16) & 1u);
    return (unsigned short)(r >> 16);
}
__device__ inline float bf16_val(unsigned short b) {
    union { float f; unsigned u; } v; v.u = ((unsigned)b) << 16;
    return v.f;
}
__device__ inline void split8(const float* p, bf16x8& h, bf16x8& l) {
    float4 a = *(const float4*)p;
    float4 b = *(const float4*)(p + 4);
    float f[8] = {a.x, a.y, a.z, a.w, b.x, b.y, b.z, b.w};
#pragma unroll
    for (int j = 0; j < 8; ++j) {
        unsigned short hb = bf16_rne(f[j]);
        float lo = f[j] - bf16_val(hb);
        h[j] = (short)hb;
        l[j] = (short)bf16_rne(lo);
    }
}

// Prep (4096 threads): fragment-linear bf16 hi/lo B-operand from emb
// ((D,K) = B[k_gemm=d][n=codeword] directly), plus embT + ||e||^2.
__global__ void vq_prep(const float* __restrict__ emb,
                        float* __restrict__ embT,
                        float* __restrict__ enorm,
                        bf16x8* __restrict__ bhi,
                        bf16x8* __restrict__ blo) {
    int t = blockIdx.x * blockDim.x + threadIdx.x;   // 0..4095
    int nt = t >> 7, c = (t >> 6) & 1, lane = t & 63;
    int k  = nt * 16 + (lane & 15);
    int d0 = c * 32 + ((lane >> 4) << 3);
    bf16x8 h, l;
#pragma unroll
    for (int j = 0; j < 8; ++j) {
        float xv = emb[(d0 + j) * K + k];
        unsigned short hb = bf16_rne(xv);
        float lo = xv - bf16_val(hb);
        h[j] = (short)hb;
        l[j] = (short)bf16_rne(lo);
    }
    int off = (nt * 2 + c) * 64 + lane;
    bhi[off] = h; blo[off] = l;

    if (t < K) {    // job 2: transpose + norms
        float s = 0.f;
#pragma unroll
        for (int d = 0; d < D; ++d) {
            float v = emb[d * K + t];
            embT[t * D + d] = v;
            s += v * v;
        }
        enorm[t] = s;
    }
}

// Fused main (round-5 proven structure: wave = 2 row-tiles x full codebook,
// 512 blocks, wave-independent epilogue) + LDS double-buffered B-staging
// (T3 2-phase: all 4 waves consume the same 4KB/tile stream; each thread
// stages 16B; global prefetch issued one iteration ahead; 1 barrier/tile).
// Codebook-split occupancy attempts (R7/R9) carried ~26-36 MB mystery writes
// and 3x slowdown — abandoned. Proxy = -0.5*||e||^2 + x.e via 3-product
// bf16-split MFMA (argmax == argmin of true distance). Top-2 tracked;
// margin<TAU rows re-solved exactly in fp32 inline (chunked x, R9-proven).
__global__ __launch_bounds__(256, 2) void vq_mfma(
    const float* __restrict__ x,
    const float* __restrict__ embT,
    const float* __restrict__ enorm,
    const bf16x8* __restrict__ bhi,
    const bf16x8* __restrict__ blo,
    float* __restrict__ outq,
    float* __restrict__ outidx) {
    const int tid  = threadIdx.x;
    const int wave = __builtin_amdgcn_readfirstlane(tid >> 6);
    const int lane = tid & 63;
    const int col  = lane & 15;   // A-row-in-tile for A-frag; codeword for B/C
    const int grp  = lane >> 4;
    const int rt0  = (blockIdx.x * 4 + wave) * 2;

    // staged B tile: [0..63]=bhi c0, [64..127]=bhi c1, [128..191]=blo c0,
    // [192..255]=blo c1  (matches fo = nt*128 + c*64 + lane)
    __shared__ bf16x8 sB[2][256];

    // A fragments (16x16x32): row m = lane&15, k = (lane>>4)*8 + j (+32*c)
    bf16x8 ah[2][2], al[2][2];
#pragma unroll
    for (int t = 0; t < 2; ++t) {
        const float* xr = x + (size_t)((rt0 + t) * 16 + col) * D + grp * 8;
        split8(xr,      ah[t][0], al[t][0]);
        split8(xr + 32, ah[t][1], al[t][1]);
    }

    float b1[2][4], b2[2][4];
    int   bi[2][4];
#pragma unroll
    for (int t = 0; t < 2; ++t)
#pragma unroll
        for (int q = 0; q < 4; ++q) {
            b1[t][q] = -3.4e38f; b2[t][q] = -3.4e38f; bi[t][q] = 0;
        }

    // staging prologue: tile 0 into sB[0]; tile 1 load in flight
    bf16x8 pf = (tid < 128) ? bhi[tid] : blo[tid - 128];
    sB[0][tid] = pf;
    pf = (tid < 128) ? bhi[128 + tid] : blo[tid];   // tile 1 (128+(tid-128))
    __syncthreads();

    const f32x4 zero4 = {0.f, 0.f, 0.f, 0.f};
    for (int nt = 0; nt < NT; ++nt) {
        const int cur = nt & 1;
        if (nt + 1 < NT) sB[cur ^ 1][tid] = pf;          // write next tile
        if (nt + 2 < NT)                                  // issue load 2 ahead
            pf = (tid < 128) ? bhi[(nt + 2) * 128 + tid]
                             : blo[(nt + 2) * 128 + (tid - 128)];

        bf16x8 bh0 = sB[cur][lane],       bh1 = sB[cur][64 + lane];
        bf16x8 bl0 = sB[cur][128 + lane], bl1 = sB[cur][192 + lane];
        float env2 = enorm[nt * 16 + col] * -0.5f;
        int kk = nt * 16 + col;
#pragma unroll
        for (int t = 0; t < 2; ++t) {
            f32x4 hh = __builtin_amdgcn_mfma_f32_16x16x32_bf16(ah[t][0], bh0, zero4, 0, 0, 0);
            f32x4 hl = __builtin_amdgcn_mfma_f32_16x16x32_bf16(ah[t][0], bl0, zero4, 0, 0, 0);
            f32x4 lh = __builtin_amdgcn_mfma_f32_16x16x32_bf16(al[t][0], bh0, zero4, 0, 0, 0);
            hh = __builtin_amdgcn_mfma_f32_16x16x32_bf16(ah[t][1], bh1, hh, 0, 0, 0);
            hl = __builtin_amdgcn_mfma_f32_16x16x32_bf16(ah[t][1], bl1, hl, 0, 0, 0);
            lh = __builtin_amdgcn_mfma_f32_16x16x32_bf16(al[t][1], bh1, lh, 0, 0, 0);
#pragma unroll
            for (int q = 0; q < 4; ++q) {
                float v = (hh[q] + hl[q]) + (lh[q] + env2);
                bool gt = v > b1[t][q];                         // strict: first k wins
                b2[t][q] = fmaxf(b2[t][q], fminf(b1[t][q], v)); // uses OLD b1
                b1[t][q] = gt ? v : b1[t][q];
                bi[t][q] = gt ? kk : bi[t][q];
            }
        }
        __syncthreads();   // readers of sB[cur] done; sB[cur^1] writes visible
    }

    // reduce across the 16 codeword-columns within each 16-lane group;
    // afterwards all 16 lanes of group g hold consensus for its rows.
#pragma unroll
    for (int t = 0; t < 2; ++t)
#pragma unroll
        for (int q = 0; q < 4; ++q) {
            float v1 = b1[t][q], v2 = b2[t][q];
            int   i1 = bi[t][q];
#pragma unroll
            for (int m = 1; m <= 8; m <<= 1) {
                float o1 = __shfl_xor(v1, m);
                float o2 = __shfl_xor(v2, m);
                int   oi = __shfl_xor(i1, m);
                float nb2 = fmaxf(fminf(v1, o1), fmaxf(v2, o2));
                if (o1 > v1 || (o1 == v1 && oi < i1)) { v1 = o1; i1 = oi; }
                v2 = nb2;
            }
            b1[t][q] = v1; b2[t][q] = v2; bi[t][q] = i1;
        }

    // inline exact fp32 re-solve for near-tie rows (wave-uniform control).
    // Lane owns codewords k = lane*8 .. lane*8+7; x accessed in 4 chunks.
#pragma unroll
    for (int t = 0; t < 2; ++t)
#pragma unroll
        for (int q = 0; q < 4; ++q) {
            unsigned long long m = __ballot(b1[t][q] - b2[t][q] < TAU);
            if (m == 0ull) continue;                  // wave-uniform skip
            for (int g = 0; g < 4; ++g) {
                if (!((m >> (g * 16)) & 1ull)) continue;
                int row = (rt0 + t) * 16 + g * 4 + q; // wave-uniform
                const float4* x4 = (const float4*)(x + (size_t)row * D);
                float xn = 0.f;
                float dd[8];
#pragma unroll
                for (int kk = 0; kk < 8; ++kk) dd[kk] = 0.f;
#pragma unroll
                for (int c = 0; c < 4; ++c) {
                    float4 xc0 = x4[c*4+0], xc1 = x4[c*4+1];
                    float4 xc2 = x4[c*4+2], xc3 = x4[c*4+3];
                    xn += xc0.x*xc0.x + xc0.y*xc0.y + xc0.z*xc0.z + xc0.w*xc0.w
                        + xc1.x*xc1.x + xc1.y*xc1.y + xc1.z*xc1.z + xc1.w*xc1.w
                        + xc2.x*xc2.x + xc2.y*xc2.y + xc2.z*xc2.z + xc2.w*xc2.w
                        + xc3.x*xc3.x + xc3.y*xc3.y + xc3.z*xc3.z + xc3.w*xc3.w;
#pragma unroll
                    for (int kk = 0; kk < 8; ++kk) {
                        const float4* e4 =
                            (const float4*)(embT + (size_t)(lane * 8 + kk) * D) + c * 4;
                        float4 e0 = e4[0], e1 = e4[1], e2 = e4[2], e3 = e4[3];
                        dd[kk] += xc0.x*e0.x + xc0.y*e0.y + xc0.z*e0.z + xc0.w*e0.w
                                + xc1.x*e1.x + xc1.y*e1.y + xc1.z*e1.z + xc1.w*e1.w
                                + xc2.x*e2.x + xc2.y*e2.y + xc2.z*e2.z + xc2.w*e2.w
                                + xc3.x*e3.x + xc3.y*e3.y + xc3.z*e3.z + xc3.w*e3.w;
                    }
                }
                float best = 3.4e38f; int bb = 0;
#pragma unroll
                for (int kk = 0; kk < 8; ++kk) {      // ascending k within lane
                    int k = lane * 8 + kk;
                    float dist = (xn + enorm[k]) - 2.0f * dd[kk];
                    if (dist < best) { best = dist; bb = k; }
                }
#pragma unroll
                for (int mm = 1; mm <= 32; mm <<= 1) {
                    float od = __shfl_xor(best, mm);
                    int   oi = __shfl_xor(bb, mm);
                    if (od < best || (od == best && oi < bb)) { best = od; bb = oi; }
                }
                if (grp == g) bi[t][q] = bb;   // patch owner group's consensus
            }
        }

    // writes: C-layout row = (lane>>4)*4 + q, col = lane&15
#pragma unroll
    for (int t = 0; t < 2; ++t) {
        int rbase = (rt0 + t) * 16;
#pragma unroll
        for (int q = 0; q < 4; ++q) {
            if (col == q) {
                int row = rbase + grp * 4 + q;
                outidx[row] = (float)bi[t][q];
            }
        }
#pragma unroll
        for (int g = 0; g < 4; ++g)
#pragma unroll
            for (int q = 0; q < 4; ++q) {
                int kidx = __shfl(bi[t][q], g * 16);
                int row  = rbase + g * 4 + q;
                outq[(size_t)row * D + lane] = embT[(size_t)kidx * D + lane];
            }
    }
}

extern "C" void kernel_launch(void* const* d_in, const int* in_sizes, int n_in,
                              void* d_out, int out_size, void* d_ws, size_t ws_size,
                              hipStream_t stream) {
    const float* x   = (const float*)d_in[0];   // (64,32,32,64) f32
    const float* emb = (const float*)d_in[1];   // (64,512) f32
    int nrows = in_sizes[0] / D;                // 65536

    char* w = (char*)d_ws;
    float*  embT   = (float*)w;   w += (size_t)K * D * 4;        // 128 KiB
    float*  enorm  = (float*)w;   w += (size_t)K * 4;            // 2 KiB
    bf16x8* bhi    = (bf16x8*)w;  w += (size_t)NT * 2 * 64 * 16; // 64 KiB
    bf16x8* blo    = (bf16x8*)w;                                 // 64 KiB

    float* outq   = (float*)d_out;
    float* outidx = (float*)d_out + (size_t)nrows * D;

    vq_prep<<<16, 256, 0, stream>>>(emb, embT, enorm, bhi, blo);
    vq_mfma<<<nrows / 128, 256, 0, stream>>>(x, embT, enorm, bhi, blo,
                                             outq, outidx);
}

// Round 11
// 47.404 us; speedup vs baseline: 2.4441x; 1.4541x over previous
//
#include <hip/hip_runtime.h>

#define D 64
#define K 512
#define NT (K / 16)          // 32 codeword tiles
#define TAU 0.01f            // proxy-margin threshold (dist-gap 0.02)

typedef float  f32x4  __attribute__((ext_vector_type(4)));
typedef short  bf16x8 __attribute__((ext_vector_type(8)));

__device__ inline unsigned short bf16_rne(float f) {
    union { float f; unsigned u; } v; v.f = f;
    unsigned r = v.u + 0x7FFFu + ((v.u >> 16) & 1u);
    return (unsigned short)(r >> 16);
}
__device__ inline float bf16_val(unsigned short b) {
    union { float f; unsigned u; } v; v.u = ((unsigned)b) << 16;
    return v.f;
}
__device__ inline void split8(const float* p, bf16x8& h, bf16x8& l) {
    float4 a = *(const float4*)p;
    float4 b = *(const float4*)(p + 4);
    float f[8] = {a.x, a.y, a.z, a.w, b.x, b.y, b.z, b.w};
#pragma unroll
    for (int j = 0; j < 8; ++j) {
        unsigned short hb = bf16_rne(f[j]);
        float lo = f[j] - bf16_val(hb);
        h[j] = (short)hb;
        l[j] = (short)bf16_rne(lo);
    }
}

// Prep (4096 threads): fragment-linear bf16 hi/lo B-operand from emb
// ((D,K) = B[k_gemm=d][n=codeword] directly), plus embT + ||e||^2.
__global__ void vq_prep(const float* __restrict__ emb,
                        float* __restrict__ embT,
                        float* __restrict__ enorm,
                        bf16x8* __restrict__ bhi,
                        bf16x8* __restrict__ blo) {
    int t = blockIdx.x * blockDim.x + threadIdx.x;   // 0..4095
    int nt = t >> 7, c = (t >> 6) & 1, lane = t & 63;
    int k  = nt * 16 + (lane & 15);
    int d0 = c * 32 + ((lane >> 4) << 3);
    bf16x8 h, l;
#pragma unroll
    for (int j = 0; j < 8; ++j) {
        float xv = emb[(d0 + j) * K + k];
        unsigned short hb = bf16_rne(xv);
        float lo = xv - bf16_val(hb);
        h[j] = (short)hb;
        l[j] = (short)bf16_rne(lo);
    }
    int off = (nt * 2 + c) * 64 + lane;
    bhi[off] = h; blo[off] = l;

    if (t < K) {    // job 2: transpose + norms
        float s = 0.f;
#pragma unroll
        for (int d = 0; d < D; ++d) {
            float v = emb[d * K + t];
            embT[t * D + d] = v;
            s += v * v;
        }
        enorm[t] = s;
    }
}

// Fused main — round-5 proven structure (wave = 2 row-tiles x full codebook,
// 512 blocks, no LDS, wave-independent epilogue, xr[16] exact re-solve),
// with two deltas:
//  (a) hh/hl/lh 3-chain MFMA + late env2 (R9/R10-correctness-proven) for ILP;
//  (b) REGISTER double-buffer of the 4 B-fragments + enorm, prefetched one
//      tile ahead (R10 post-mortem: LDS staging hurt — barriers + round-trip;
//      the stall is exposed L2 latency at 2 waves/SIMD, so issue tile-(n+1)
//      loads before tile-n's MFMA block and let compute cover the latency).
__global__ __launch_bounds__(256, 2) void vq_mfma(
    const float* __restrict__ x,
    const float* __restrict__ embT,
    const float* __restrict__ enorm,
    const bf16x8* __restrict__ bhi,
    const bf16x8* __restrict__ blo,
    float* __restrict__ outq,
    float* __restrict__ outidx) {
    const int tid  = threadIdx.x;
    const int wave = __builtin_amdgcn_readfirstlane(tid >> 6);
    const int lane = tid & 63;
    const int col  = lane & 15;   // A-row-in-tile for A-frag; codeword for B/C
    const int grp  = lane >> 4;
    const int rt0  = (blockIdx.x * 4 + wave) * 2;

    // A fragments (16x16x32): row m = lane&15, k = (lane>>4)*8 + j (+32*c)
    bf16x8 ah[2][2], al[2][2];
#pragma unroll
    for (int t = 0; t < 2; ++t) {
        const float* xr = x + (size_t)((rt0 + t) * 16 + col) * D + grp * 8;
        split8(xr,      ah[t][0], al[t][0]);
        split8(xr + 32, ah[t][1], al[t][1]);
    }

    float b1[2][4], b2[2][4];
    int   bi[2][4];
#pragma unroll
    for (int t = 0; t < 2; ++t)
#pragma unroll
        for (int q = 0; q < 4; ++q) {
            b1[t][q] = -3.4e38f; b2[t][q] = -3.4e38f; bi[t][q] = 0;
        }

    // register prefetch of tile 0's B-fragments + norm
    bf16x8 nh0 = bhi[lane], nh1 = bhi[64 + lane];
    bf16x8 nl0 = blo[lane], nl1 = blo[64 + lane];
    float  nen = enorm[col];

    const f32x4 zero4 = {0.f, 0.f, 0.f, 0.f};
    for (int nt = 0; nt < NT; ++nt) {
        bf16x8 bh0 = nh0, bh1 = nh1, bl0 = nl0, bl1 = nl1;
        float env2 = nen * -0.5f;
        int kk = nt * 16 + col;
        if (nt + 1 < NT) {               // issue next tile's loads NOW;
            int fo = (nt + 1) * 128 + lane;   // consumed next iteration
            nh0 = bhi[fo]; nh1 = bhi[fo + 64];
            nl0 = blo[fo]; nl1 = blo[fo + 64];
            nen = enorm[(nt + 1) * 16 + col];
        }
#pragma unroll
        for (int t = 0; t < 2; ++t) {
            f32x4 hh = __builtin_amdgcn_mfma_f32_16x16x32_bf16(ah[t][0], bh0, zero4, 0, 0, 0);
            f32x4 hl = __builtin_amdgcn_mfma_f32_16x16x32_bf16(ah[t][0], bl0, zero4, 0, 0, 0);
            f32x4 lh = __builtin_amdgcn_mfma_f32_16x16x32_bf16(al[t][0], bh0, zero4, 0, 0, 0);
            hh = __builtin_amdgcn_mfma_f32_16x16x32_bf16(ah[t][1], bh1, hh, 0, 0, 0);
            hl = __builtin_amdgcn_mfma_f32_16x16x32_bf16(ah[t][1], bl1, hl, 0, 0, 0);
            lh = __builtin_amdgcn_mfma_f32_16x16x32_bf16(al[t][1], bh1, lh, 0, 0, 0);
#pragma unroll
            for (int q = 0; q < 4; ++q) {
                float v = (hh[q] + hl[q]) + (lh[q] + env2);
                bool gt = v > b1[t][q];                         // strict: first k wins
                b2[t][q] = fmaxf(b2[t][q], fminf(b1[t][q], v)); // uses OLD b1
                b1[t][q] = gt ? v : b1[t][q];
                bi[t][q] = gt ? kk : bi[t][q];
            }
        }
    }

    // reduce across the 16 codeword-columns within each 16-lane group;
    // afterwards all 16 lanes of group g hold consensus for its rows.
#pragma unroll
    for (int t = 0; t < 2; ++t)
#pragma unroll
        for (int q = 0; q < 4; ++q) {
            float v1 = b1[t][q], v2 = b2[t][q];
            int   i1 = bi[t][q];
#pragma unroll
            for (int m = 1; m <= 8; m <<= 1) {
                float o1 = __shfl_xor(v1, m);
                float o2 = __shfl_xor(v2, m);
                int   oi = __shfl_xor(i1, m);
                float nb2 = fmaxf(fminf(v1, o1), fmaxf(v2, o2));
                if (o1 > v1 || (o1 == v1 && oi < i1)) { v1 = o1; i1 = oi; }
                v2 = nb2;
            }
            b1[t][q] = v1; b2[t][q] = v2; bi[t][q] = i1;
        }

    // inline exact fp32 re-solve for near-tie rows (wave-uniform control).
    // Lane owns codewords k = lane*8 .. lane*8+7 (R5-proven xr[16] variant —
    // the chunked variant correlates with ~25 MB mystery scratch writes).
#pragma unroll
    for (int t = 0; t < 2; ++t)
#pragma unroll
        for (int q = 0; q < 4; ++q) {
            unsigned long long m = __ballot(b1[t][q] - b2[t][q] < TAU);
            if (m == 0ull) continue;                  // wave-uniform skip
            for (int g = 0; g < 4; ++g) {
                if (!((m >> (g * 16)) & 1ull)) continue;
                int row = (rt0 + t) * 16 + g * 4 + q; // wave-uniform
                const float4* x4 = (const float4*)(x + (size_t)row * D);
                float4 xr[16];
#pragma unroll
                for (int j = 0; j < 16; ++j) xr[j] = x4[j];
                float xn = 0.f;
#pragma unroll
                for (int j = 0; j < 16; ++j)
                    xn += xr[j].x * xr[j].x + xr[j].y * xr[j].y +
                          xr[j].z * xr[j].z + xr[j].w * xr[j].w;
                float best = 3.4e38f; int bb = 0;
#pragma unroll
                for (int kk = 0; kk < 8; ++kk) {
                    int k = lane * 8 + kk;
                    const float4* e4 = (const float4*)(embT + (size_t)k * D);
                    float d0 = 0.f, d1 = 0.f, d2 = 0.f, d3 = 0.f;
#pragma unroll
                    for (int j = 0; j < 4; ++j) {
                        float4 e0 = e4[j*4+0], e1 = e4[j*4+1];
                        float4 e2 = e4[j*4+2], e3 = e4[j*4+3];
                        d0 += xr[j*4+0].x*e0.x + xr[j*4+0].y*e0.y + xr[j*4+0].z*e0.z + xr[j*4+0].w*e0.w;
                        d1 += xr[j*4+1].x*e1.x + xr[j*4+1].y*e1.y + xr[j*4+1].z*e1.z + xr[j*4+1].w*e1.w;
                        d2 += xr[j*4+2].x*e2.x + xr[j*4+2].y*e2.y + xr[j*4+2].z*e2.z + xr[j*4+2].w*e2.w;
                        d3 += xr[j*4+3].x*e3.x + xr[j*4+3].y*e3.y + xr[j*4+3].z*e3.z + xr[j*4+3].w*e3.w;
                    }
                    float dist = (xn + enorm[k]) - 2.0f * ((d0 + d1) + (d2 + d3));
                    if (dist < best) { best = dist; bb = k; }  // ascending k
                }
#pragma unroll
                for (int mm = 1; mm <= 32; mm <<= 1) {
                    float od = __shfl_xor(best, mm);
                    int   oi = __shfl_xor(bb, mm);
                    if (od < best || (od == best && oi < bb)) { best = od; bb = oi; }
                }
                if (grp == g) bi[t][q] = bb;   // patch owner group's result
            }
        }

    // writes: C-layout row = (lane>>4)*4 + q, col = lane&15
#pragma unroll
    for (int t = 0; t < 2; ++t) {
        int rbase = (rt0 + t) * 16;
#pragma unroll
        for (int q = 0; q < 4; ++q) {
            if (col == q) {
                int row = rbase + grp * 4 + q;
                outidx[row] = (float)bi[t][q];
            }
        }
#pragma unroll
        for (int g = 0; g < 4; ++g)
#pragma unroll
            for (int q = 0; q < 4; ++q) {
                int kidx = __shfl(bi[t][q], g * 16);
                int row  = rbase + g * 4 + q;
                outq[(size_t)row * D + lane] = embT[(size_t)kidx * D + lane];
            }
    }
}

extern "C" void kernel_launch(void* const* d_in, const int* in_sizes, int n_in,
                              void* d_out, int out_size, void* d_ws, size_t ws_size,
                              hipStream_t stream) {
    const float* x   = (const float*)d_in[0];   // (64,32,32,64) f32
    const float* emb = (const float*)d_in[1];   // (64,512) f32
    int nrows = in_sizes[0] / D;                // 65536

    char* w = (char*)d_ws;
    float*  embT   = (float*)w;   w += (size_t)K * D * 4;        // 128 KiB
    float*  enorm  = (float*)w;   w += (size_t)K * 4;            // 2 KiB
    bf16x8* bhi    = (bf16x8*)w;  w += (size_t)NT * 2 * 64 * 16; // 64 KiB
    bf16x8* blo    = (bf16x8*)w;                                 // 64 KiB

    float* outq   = (float*)d_out;
    float* outidx = (float*)d_out + (size_t)nrows * D;

    vq_prep<<<16, 256, 0, stream>>>(emb, embT, enorm, bhi, blo);
    vq_mfma<<<nrows / 128, 256, 0, stream>>>(x, embT, enorm, bhi, blo,
                                             outq, outidx);
}